// Round 14
// baseline (79.886 us; speedup 1.0000x reference)
//
#include <hip/hip_runtime.h>
#include <math.h>
#include <stdint.h>

#define K_NN   16
#define BATCH  2
#define NA_    16384
#define NB_    8192
#define CH     128
// coords are [z,y,x]: z in [0,64), y in [0,256), x in [0,256); cell edge 16
#define CZ     4
#define CY     16
#define CX     16
#define NCELL  (CZ*CY*CX)   // 1024
#define CSH    4
#define PADKEY 0xFFF00000u  // > any real key ((134019<<14)|16383 = 0x82E0BFFF)

// ws layout:
//   counts : [B][NCELL] int  @ 0      (8 KiB)   -- memset 0 each call
//   ticket : int             @ 8192                (memset with counts)
//   flag   : int             @ 8196                (memset with counts)
//   meta   : [B][NCELL] int2 @ 16384  (16 KiB)
//   cursor : [B][NCELL] int  @ 32768  (8 KiB)
//   sorted : [B][NA] float4  @ 49152  (512 KiB)
#define OFF_TICKET 8192
#define OFF_FLAG   8196
#define OFF_META   16384
#define OFF_CURSOR 32768
#define OFF_SORTED 49152
#define NBLD       128      // build blocks (all co-resident: spin is safe)

__device__ __forceinline__ int cell_of(float p0, float p1, float p2) {
    const int cz = ((int)p0) >> CSH;   // z/16 in [0,4)
    const int cy = ((int)p1) >> CSH;   // y/16 in [0,16)
    const int cx = ((int)p2) >> CSH;   // x/16 in [0,16)
    return (cz * CY + cy) * CX + cx;
}

// ---------------- fused build: hist -> (last block) scan -> scatter ----------------

__global__ __launch_bounds__(256) void build_fused(const float* __restrict__ tpos,
                                                   int* __restrict__ counts,
                                                   int* __restrict__ ticket,
                                                   int* __restrict__ flag,
                                                   int2* __restrict__ meta,
                                                   int* __restrict__ cursor,
                                                   float4* __restrict__ sorted) {
    __shared__ int wp[4];
    __shared__ int isLast;

    const int tid = threadIdx.x;
    const int i = blockIdx.x * 256 + tid;          // over B*NA = 32768
    const int b = i >> 14;

    // ---- phase 1: histogram (device-scope atomics: XCD-coherent) ----
    const float* tp = tpos + (size_t)i * 3;
    const float p0 = tp[0], p1 = tp[1], p2 = tp[2];
    const int cell = b * NCELL + cell_of(p0, p1, p2);
    atomicAdd(&counts[cell], 1);
    __syncthreads();                                // drains this block's atomics
    __threadfence();
    if (tid == 0) isLast = (atomicAdd(ticket, 1) == NBLD - 1);
    __syncthreads();

    if (isLast) {
        // ---- phase 2: scan both batches' 1024 cells (4 cells/thread) ----
        const int lane = tid & 63, w = tid >> 6;
        for (int b2 = 0; b2 < BATCH; ++b2) {
            const int cbase = b2 * NCELL + tid * 4;
            const int c0 = atomicAdd(&counts[cbase + 0], 0);
            const int c1 = atomicAdd(&counts[cbase + 1], 0);
            const int c2 = atomicAdd(&counts[cbase + 2], 0);
            const int c3 = atomicAdd(&counts[cbase + 3], 0);
            const int tsum = c0 + c1 + c2 + c3;
            int x = tsum;
#pragma unroll
            for (int off = 1; off < 64; off <<= 1) {
                int u = __shfl_up(x, off);
                if (lane >= off) x += u;
            }
            if (lane == 63) wp[w] = x;
            __syncthreads();
            if (tid == 0) {
                int r = 0;
#pragma unroll
                for (int k = 0; k < 4; ++k) { const int v = wp[k]; wp[k] = r; r += v; }
            }
            __syncthreads();
            const int e0 = x - tsum + wp[w];
            const int e1 = e0 + c0;
            const int e2 = e1 + c1;
            const int e3 = e2 + c2;
            meta[cbase + 0] = make_int2(e0, c0);
            meta[cbase + 1] = make_int2(e1, c1);
            meta[cbase + 2] = make_int2(e2, c2);
            meta[cbase + 3] = make_int2(e3, c3);
            atomicExch(&cursor[cbase + 0], e0);     // atomic: coherent for scatter readers
            atomicExch(&cursor[cbase + 1], e1);
            atomicExch(&cursor[cbase + 2], e2);
            atomicExch(&cursor[cbase + 3], e3);
            __syncthreads();
        }
        __threadfence();
        __syncthreads();
        if (tid == 0) atomicExch(flag, 1);
    } else {
        if (tid == 0) {
            while (atomicAdd(flag, 0) == 0) { __builtin_amdgcn_s_sleep(2); }
        }
        __syncthreads();
    }

    // ---- phase 3: scatter (cursor via coherent atomics) ----
    const int pos = atomicAdd(&cursor[cell], 1);
    sorted[(size_t)b * NA_ + pos] = make_float4(p0, p1, p2, __int_as_float(i & (NA_ - 1)));
}

// ---------------- fallback merge: extract 16 smallest keys across the wave ----------------

template<int NS>
__device__ __forceinline__ void merge_extract(uint32_t (&k)[NS], uint32_t (&sel)[K_NN]) {
    uint32_t m = k[0];
#pragma unroll
    for (int j = 1; j < NS; ++j) m = min(m, k[j]);
#pragma unroll
    for (int r = 0; r < K_NN; ++r) {
        uint32_t v = m;
#pragma unroll
        for (int off = 32; off > 0; off >>= 1)
            v = min(v, (uint32_t)__shfl_xor((int)v, off));
        sel[r] = (uint32_t)__builtin_amdgcn_readfirstlane((int)v);
        if (m == v) {
#pragma unroll
            for (int j = 0; j < NS; ++j) k[j] = (k[j] == v) ? 0xFFFFFFFFu : k[j];
            m = k[0];
#pragma unroll
            for (int j = 1; j < NS; ++j) m = min(m, k[j]);
        }
    }
}

// ---------------- main KNN + aggregation (R13 structure, measured 45.0 us) ----------------

__global__ __launch_bounds__(256) void knn_cells_kernel(
    const float* __restrict__ tfeat,   // [B, NA, C]
    const float* __restrict__ spos,    // [B, NB, 3]
    const int2*  __restrict__ meta,    // [B, NCELL] (start, count)
    const float4* __restrict__ sorted, // [B, NA] (z,y,x,idx-bits)
    float* __restrict__ out)           // [B, NB, C]
{
    __shared__ uint32_t sKeys[4][132];
    __shared__ uint32_t sSel[4][16];

    const int tid  = threadIdx.x;
    const int lane = tid & 63;
    const int wave = tid >> 6;

    const int bpb = NB_ / 4;
    const int b = blockIdx.x / bpb;
    const int n = (blockIdx.x % bpb) * 4 + wave;

    const float* sp = spos + ((size_t)b * NB_ + n) * 3;
    const float s0 = sp[0], s1 = sp[1], s2 = sp[2];     // z, y, x
    const int scz = __builtin_amdgcn_readfirstlane(((int)s0) >> CSH);
    const int scy = __builtin_amdgcn_readfirstlane(((int)s1) >> CSH);
    const int scx = __builtin_amdgcn_readfirstlane(((int)s2) >> CSH);

    int rcov = max(max(scx, CX - 1 - scx), max(scy, CY - 1 - scy));
    rcov = max(rcov, max(scz, CZ - 1 - scz));

    const int2*   mb = meta   + (size_t)b * NCELL;
    const float4* sb = sorted + (size_t)b * NA_;

    // ---- 9 contiguous row-ranges of the 3x3x3 box (wave-uniform scalars) ----
    int rstart[9], rlen[9];
    const int cxlo = max(scx - 1, 0), cxhi = min(scx + 1, CX - 1);
    int nov = 0; bool fast = true;
#pragma unroll
    for (int kk = 0; kk < 9; ++kk) {
        const int cz = scz + kk / 3 - 1, cy = scy + kk % 3 - 1;
        int st = 0, ln = 0;
        if ((unsigned)cz < CZ && (unsigned)cy < CY) {
            const int rowb = (cz * CY + cy) * CX;
            const int2 mlo = mb[rowb + cxlo];
            const int2 mhi = mb[rowb + cxhi];
            st = mlo.x; ln = mhi.x + mhi.y - mlo.x;
        }
        rstart[kk] = st; rlen[kk] = ln;
        if (ln > 64) ++nov;
        if (ln > 128) fast = false;
    }
    if (nov > 3) fast = false;

    uint32_t sel[K_NN];
    bool done = false;

    if (fast) {
        // ---------- slotted scan: no selection logic ----------
        uint32_t key[12];
#pragma unroll
        for (int j = 0; j < 12; ++j) key[j] = PADKEY + j;
        int oc = 9;
#pragma unroll
        for (int kk = 0; kk < 9; ++kk) {
            if (rlen[kk] > 0) {
                const bool act = lane < rlen[kk];
                const int a = rstart[kk] + (act ? lane : 0);
                const float4 p = sb[a];
                const float d0 = s0 - p.x, d1 = s1 - p.y, d2c = s2 - p.z;
                const float d2 = d0 * d0 + d1 * d1 + d2c * d2c;
                const uint32_t kv = ((uint32_t)d2 << 14) | (uint32_t)__float_as_int(p.w);
                key[kk] = act ? kv : key[kk];
            }
            if (rlen[kk] > 64) {
                const int j2 = 64 + lane;
                const bool act = j2 < rlen[kk];
                const int a = rstart[kk] + (act ? j2 : 0);
                const float4 p = sb[a];
                const float d0 = s0 - p.x, d1 = s1 - p.y, d2c = s2 - p.z;
                const float d2 = d0 * d0 + d1 * d1 + d2c * d2c;
                const uint32_t kv = ((uint32_t)d2 << 14) | (uint32_t)__float_as_int(p.w);
                if (oc == 9)       key[9]  = act ? kv : key[9];
                else if (oc == 10) key[10] = act ? kv : key[10];
                else               key[11] = act ? kv : key[11];
                ++oc;
            }
        }

        // ---------- two-tier census (packed) ----------
        const uint32_t KT1 = 169u << 14;   // d^2 < 169
        const uint32_t KT2 = 288u << 14;   // d^2 < 288 (ring-1 stop: outside box >= 289)
        uint32_t pc = 0;
#pragma unroll
        for (int j = 0; j < 12; ++j) {
            pc += (key[j] < KT1) ? 1u : 0u;
            pc += (key[j] < KT2) ? 0x10000u : 0u;
        }
#pragma unroll
        for (int off = 32; off > 0; off >>= 1)
            pc += (uint32_t)__shfl_xor((int)pc, off);
        const uint32_t c1 = (uint32_t)__builtin_amdgcn_readfirstlane((int)(pc & 0xFFFFu));
        const uint32_t c2 = (uint32_t)__builtin_amdgcn_readfirstlane((int)(pc >> 16));
        uint32_t keyT = 0;
        if (c1 >= K_NN) keyT = KT1;
        else if (c2 >= K_NN) keyT = KT2;

        if (keyT) {
            // ---------- ballot compaction into wave-private LDS ----------
            int nsel = 0;
#pragma unroll
            for (int j = 0; j < 12; ++j) {
                const bool pred = key[j] < keyT;
                const unsigned long long m = __ballot(pred);
                const int offp = __builtin_amdgcn_mbcnt_hi(
                    (uint32_t)(m >> 32), __builtin_amdgcn_mbcnt_lo((uint32_t)m, 0));
                const int dst = nsel + offp;
                if (pred && dst < 132) sKeys[wave][dst] = key[j];
                nsel += (int)__builtin_popcountll(m);
            }

            if (nsel >= K_NN && nsel <= 128) {
                const int padn = (4 - (nsel & 3)) & 3;
                if (lane < padn) sKeys[wave][nsel + lane] = 0xFFFFFFFFu;
                __threadfence_block();

                const uint32_t myk0 = (lane      < nsel) ? sKeys[wave][lane]      : 0xFFFFFFFFu;
                const uint32_t myk1 = (64 + lane < nsel) ? sKeys[wave][64 + lane] : 0xFFFFFFFFu;

                uint32_t r0 = 0, r1 = 0;
                const int nmax4 = (nsel + 3) & ~3;
                for (int j = 0; j < nmax4; j += 4) {
                    const uint4 k4 = *(const uint4*)&sKeys[wave][j];
                    r0 += (k4.x < myk0) + (k4.y < myk0) + (k4.z < myk0) + (k4.w < myk0);
                    r1 += (k4.x < myk1) + (k4.y < myk1) + (k4.z < myk1) + (k4.w < myk1);
                }
                if (r0 < K_NN) sSel[wave][r0] = myk0;
                if (r1 < K_NN) sSel[wave][r1] = myk1;
                __threadfence_block();

                const uint4 sA = *(const uint4*)&sSel[wave][0];
                const uint4 sB = *(const uint4*)&sSel[wave][4];
                const uint4 sC = *(const uint4*)&sSel[wave][8];
                const uint4 sD = *(const uint4*)&sSel[wave][12];
                sel[0]  = (uint32_t)__builtin_amdgcn_readfirstlane((int)sA.x);
                sel[1]  = (uint32_t)__builtin_amdgcn_readfirstlane((int)sA.y);
                sel[2]  = (uint32_t)__builtin_amdgcn_readfirstlane((int)sA.z);
                sel[3]  = (uint32_t)__builtin_amdgcn_readfirstlane((int)sA.w);
                sel[4]  = (uint32_t)__builtin_amdgcn_readfirstlane((int)sB.x);
                sel[5]  = (uint32_t)__builtin_amdgcn_readfirstlane((int)sB.y);
                sel[6]  = (uint32_t)__builtin_amdgcn_readfirstlane((int)sB.z);
                sel[7]  = (uint32_t)__builtin_amdgcn_readfirstlane((int)sB.w);
                sel[8]  = (uint32_t)__builtin_amdgcn_readfirstlane((int)sC.x);
                sel[9]  = (uint32_t)__builtin_amdgcn_readfirstlane((int)sC.y);
                sel[10] = (uint32_t)__builtin_amdgcn_readfirstlane((int)sC.z);
                sel[11] = (uint32_t)__builtin_amdgcn_readfirstlane((int)sC.w);
                sel[12] = (uint32_t)__builtin_amdgcn_readfirstlane((int)sD.x);
                sel[13] = (uint32_t)__builtin_amdgcn_readfirstlane((int)sD.y);
                sel[14] = (uint32_t)__builtin_amdgcn_readfirstlane((int)sD.z);
                sel[15] = (uint32_t)__builtin_amdgcn_readfirstlane((int)sD.w);
                done = true;
            }
        }
    }

    if (!done) {
        // ---------- exact ring loop with insert path ----------
        for (int r = 1;; ++r) {
            uint32_t kl[K_NN];
#pragma unroll
            for (int j = 0; j < K_NN; ++j) kl[j] = PADKEY + 16 + j;
            if (r > 1) {
                uint32_t seed = 0xFFFFFFFFu;
#pragma unroll
                for (int j = 0; j < K_NN; ++j) if (lane == j) seed = sel[j];
                kl[0] = seed;
            }
            uint32_t curmax = kl[0];
#pragma unroll
            for (int j = 1; j < K_NN; ++j) curmax = max(curmax, kl[j]);

            for (int dz = -r; dz <= r; ++dz) {
                const int cz = scz + dz; if ((unsigned)cz >= CZ) continue;
                for (int dy = -r; dy <= r; ++dy) {
                    const int cy = scy + dy; if ((unsigned)cy >= CY) continue;
                    const int rowb = (cz * CY + cy) * CX;
                    const bool fullrow = (r == 1) || (max(abs(dz), abs(dy)) == r);
                    int xl[2], xh[2];
                    if (fullrow) {
                        xl[0] = max(scx - r, 0); xh[0] = min(scx + r, CX - 1);
                        xl[1] = 1; xh[1] = 0;
                    } else {
                        xl[0] = scx - r; xh[0] = scx - r;
                        xl[1] = scx + r; xh[1] = scx + r;
                        if (xl[0] < 0)      { xl[0] = 1; xh[0] = 0; }
                        if (xh[1] > CX - 1) { xl[1] = 1; xh[1] = 0; }
                    }
#pragma unroll
                    for (int q = 0; q < 2; ++q) {
                        if (xl[q] > xh[q]) continue;
                        const int2 mlo = mb[rowb + xl[q]];
                        const int2 mhi = mb[rowb + xh[q]];
                        const int st = mlo.x, ln = mhi.x + mhi.y - st;
                        for (int o = 0; o < ln; o += 64) {
                            const int j2 = o + lane;
                            const bool act = j2 < ln;
                            const int a = st + (act ? j2 : 0);
                            const float4 p = sb[a];
                            const float d0 = s0 - p.x, d1 = s1 - p.y, d2c = s2 - p.z;
                            const float d2 = d0 * d0 + d1 * d1 + d2c * d2c;
                            uint32_t kv = ((uint32_t)d2 << 14) | (uint32_t)__float_as_int(p.w);
                            kv = act ? kv : 0xFFFFFFFFu;
                            if (kv < curmax) {
#pragma unroll
                                for (int j = 0; j < K_NN; ++j)
                                    kl[j] = (kl[j] == curmax) ? kv : kl[j];
                                curmax = kl[0];
#pragma unroll
                                for (int j = 1; j < K_NN; ++j) curmax = max(curmax, kl[j]);
                            }
                        }
                    }
                }
            }
            merge_extract<K_NN>(kl, sel);
            const uint32_t d16 = sel[K_NN - 1] >> 14;
            if (d16 <= (uint32_t)(256 * r * r) || r >= rcov) break;
        }
    }

    // ---- weights + normalized feature aggregation (float2 per lane) ----
    float w[K_NN];
    float wsum = 0.f;
#pragma unroll
    for (int j = 0; j < K_NN; ++j) {
        w[j] = __expf(-0.5f * (float)(sel[j] >> 14));
        wsum += w[j];
    }
    const float inv = 1.0f / wsum;

    const float* fb = tfeat + (size_t)b * NA_ * CH;
    float2 acc = make_float2(0.f, 0.f);
#pragma unroll
    for (int j = 0; j < K_NN; ++j) {
        const int idx = (int)(sel[j] & 16383u);
        const float ww = w[j] * inv;
        const float2 v = ((const float2*)(fb + (size_t)idx * CH))[lane];
        acc.x += ww * v.x; acc.y += ww * v.y;
    }

    float2* o = (float2*)(out + ((size_t)b * NB_ + n) * CH);
    o[lane] = acc;
}

// ---------------- launch ----------------

extern "C" void kernel_launch(void* const* d_in, const int* in_sizes, int n_in,
                              void* d_out, int out_size, void* d_ws, size_t ws_size,
                              hipStream_t stream) {
    const float* tfeat = (const float*)d_in[0];   // [B,NA,C]
    const float* tpos  = (const float*)d_in[1];   // [B,NA,3]
    const float* spos  = (const float*)d_in[2];   // [B,NB,3]
    float* out = (float*)d_out;                   // [B,NB,C]

    char* ws = (char*)d_ws;
    int*    counts = (int*)(ws);
    int*    ticket = (int*)(ws + OFF_TICKET);
    int*    flag   = (int*)(ws + OFF_FLAG);
    int2*   meta   = (int2*)(ws + OFF_META);
    int*    cursor = (int*)(ws + OFF_CURSOR);
    float4* sorted = (float4*)(ws + OFF_SORTED);

    // zero counts + ticket + flag (contiguous [0, 8200))
    hipMemsetAsync(ws, 0, OFF_FLAG + sizeof(int), stream);
    build_fused<<<NBLD, 256, 0, stream>>>(tpos, counts, ticket, flag, meta, cursor, sorted);
    knn_cells_kernel<<<BATCH * (NB_ / 4), 256, 0, stream>>>(tfeat, spos, meta, sorted, out);
}

// Round 15
// 43.038 us; speedup vs baseline: 1.8562x; 1.8562x over previous
//
#include <hip/hip_runtime.h>
#include <math.h>
#include <stdint.h>

#define K_NN   16
#define BATCH  2
#define NA_    16384
#define NB_    8192
#define CH     128
// coords are [z,y,x]: z in [0,64), y in [0,256), x in [0,256); cell edge 16
#define CZ     4
#define CY     16
#define CX     16
#define NCELL  (CZ*CY*CX)   // 1024
#define CSH    4
#define PADKEY 0xFFF00000u  // > any real key ((134019<<14)|16383 = 0x82E0BFFF)

// ws layout:
//   partial: [16][NCELL] int   @ 0      (64 KiB)
//   meta   : [B][NCELL] int2   @ 65536  (16 KiB)
//   cursor : [B][NCELL] int    @ 81920  (8 KiB)
//   sorted : [B][NA] float4    @ 98304  (512 KiB)
#define OFF_META   65536
#define OFF_CURSOR 81920
#define OFF_SORTED 98304

__device__ __forceinline__ int cell_of(float p0, float p1, float p2) {
    const int cz = ((int)p0) >> CSH;
    const int cy = ((int)p1) >> CSH;
    const int cx = ((int)p2) >> CSH;
    return (cz * CY + cy) * CX + cx;
}

// ---------------- build 1: LDS-privatized histograms (16 blocks) ----------------

__global__ __launch_bounds__(256) void count_hist(const float* __restrict__ tpos,
                                                  int* __restrict__ partial) {
    __shared__ int h[NCELL];
    const int blk = blockIdx.x;
    const int t = threadIdx.x;
#pragma unroll
    for (int j = 0; j < NCELL / 256; ++j) h[t + j * 256] = 0;
    __syncthreads();
    const int base = blk * 2048;
#pragma unroll
    for (int i = 0; i < 8; ++i) {
        const float* p = tpos + (size_t)(base + i * 256 + t) * 3;
        atomicAdd(&h[cell_of(p[0], p[1], p[2])], 1);
    }
    __syncthreads();
#pragma unroll
    for (int j = 0; j < NCELL / 256; ++j) {
        const int c = t + j * 256;
        partial[blk * NCELL + c] = h[c];
    }
}

// ---------------- build 2: sum partials + scan (2 blocks x 1024) ----------------

__global__ __launch_bounds__(1024) void scan_kernel(const int* __restrict__ partial,
                                                    int2* __restrict__ meta,
                                                    int* __restrict__ cursor) {
    __shared__ int wp[16];
    const int b = blockIdx.x, t = threadIdx.x, lane = t & 63, w = t >> 6;
    int c = 0;
#pragma unroll
    for (int k = 0; k < 8; ++k) c += partial[(b * 8 + k) * NCELL + t];
    int x = c;
#pragma unroll
    for (int off = 1; off < 64; off <<= 1) {
        int u = __shfl_up(x, off);
        if (lane >= off) x += u;
    }
    if (lane == 63) wp[w] = x;
    __syncthreads();
    if (t < 16) {
        int v = wp[t];
#pragma unroll
        for (int off = 1; off < 16; off <<= 1) {
            int u = __shfl_up(v, off);
            if (t >= off) v += u;
        }
        wp[t] = v;
    }
    __syncthreads();
    const int excl = x - c + (w ? wp[w - 1] : 0);
    meta[b * NCELL + t]   = make_int2(excl, c);
    cursor[b * NCELL + t] = excl;
}

// ---------------- build 3: wide scatter (128 blocks) ----------------

__global__ __launch_bounds__(256) void scatter_kernel(const float* __restrict__ tpos,
                                                      int* __restrict__ cursor,
                                                      float4* __restrict__ sorted) {
    const int i = blockIdx.x * 256 + threadIdx.x;
    const int b = i >> 14;
    const float* tp = tpos + (size_t)i * 3;
    const float p0 = tp[0], p1 = tp[1], p2 = tp[2];
    const int cell = cell_of(p0, p1, p2);
    const int pos = atomicAdd(&cursor[b * NCELL + cell], 1);
    sorted[(size_t)b * NA_ + pos] = make_float4(p0, p1, p2, __int_as_float(i & (NA_ - 1)));
}

// ---------------- fallback merge: extract 16 smallest keys across the wave ----------------

template<int NS>
__device__ __forceinline__ void merge_extract(uint32_t (&k)[NS], uint32_t (&sel)[K_NN]) {
    uint32_t m = k[0];
#pragma unroll
    for (int j = 1; j < NS; ++j) m = min(m, k[j]);
#pragma unroll
    for (int r = 0; r < K_NN; ++r) {
        uint32_t v = m;
#pragma unroll
        for (int off = 32; off > 0; off >>= 1)
            v = min(v, (uint32_t)__shfl_xor((int)v, off));
        sel[r] = (uint32_t)__builtin_amdgcn_readfirstlane((int)v);
        if (m == v) {
#pragma unroll
            for (int j = 0; j < NS; ++j) k[j] = (k[j] == v) ? 0xFFFFFFFFu : k[j];
            m = k[0];
#pragma unroll
            for (int j = 1; j < NS; ++j) m = min(m, k[j]);
        }
    }
}

// ---------------- exact ring fallback (rare; winners -> wave-private LDS) ----------------

__device__ __noinline__ void ring_fallback(int lane, float s0, float s1, float s2,
                                           int scz, int scy, int scx, int rcov,
                                           const int2* __restrict__ mb,
                                           const float4* __restrict__ sb,
                                           uint32_t* selLds) {
    uint32_t sel[K_NN];
#pragma unroll
    for (int j = 0; j < K_NN; ++j) sel[j] = 0xFFFFFFFFu;

    for (int r = 1;; ++r) {
        uint32_t kl[K_NN];
#pragma unroll
        for (int j = 0; j < K_NN; ++j) kl[j] = PADKEY + 16 + j;
        if (r > 1) {
            uint32_t seed = 0xFFFFFFFFu;
#pragma unroll
            for (int j = 0; j < K_NN; ++j) if (lane == j) seed = sel[j];
            kl[0] = seed;
        }
        uint32_t curmax = kl[0];
#pragma unroll
        for (int j = 1; j < K_NN; ++j) curmax = max(curmax, kl[j]);

        for (int dz = -r; dz <= r; ++dz) {
            const int cz = scz + dz; if ((unsigned)cz >= CZ) continue;
            for (int dy = -r; dy <= r; ++dy) {
                const int cy = scy + dy; if ((unsigned)cy >= CY) continue;
                const int rowb = (cz * CY + cy) * CX;
                const bool fullrow = (r == 1) || (max(abs(dz), abs(dy)) == r);
                int xl[2], xh[2];
                if (fullrow) {
                    xl[0] = max(scx - r, 0); xh[0] = min(scx + r, CX - 1);
                    xl[1] = 1; xh[1] = 0;
                } else {
                    xl[0] = scx - r; xh[0] = scx - r;
                    xl[1] = scx + r; xh[1] = scx + r;
                    if (xl[0] < 0)      { xl[0] = 1; xh[0] = 0; }
                    if (xh[1] > CX - 1) { xl[1] = 1; xh[1] = 0; }
                }
#pragma unroll
                for (int q = 0; q < 2; ++q) {
                    if (xl[q] > xh[q]) continue;
                    const int2 mlo = mb[rowb + xl[q]];
                    const int2 mhi = mb[rowb + xh[q]];
                    const int st = mlo.x, ln = mhi.x + mhi.y - st;
                    for (int o = 0; o < ln; o += 64) {
                        const int j2 = o + lane;
                        const bool act = j2 < ln;
                        const int a = st + (act ? j2 : 0);
                        const float4 p = sb[a];
                        const float d0 = s0 - p.x, d1 = s1 - p.y, d2c = s2 - p.z;
                        const float d2 = d0 * d0 + d1 * d1 + d2c * d2c;
                        uint32_t kv = ((uint32_t)d2 << 14) | (uint32_t)__float_as_int(p.w);
                        kv = act ? kv : 0xFFFFFFFFu;
                        if (kv < curmax) {
#pragma unroll
                            for (int j = 0; j < K_NN; ++j)
                                kl[j] = (kl[j] == curmax) ? kv : kl[j];
                            curmax = kl[0];
#pragma unroll
                            for (int j = 1; j < K_NN; ++j) curmax = max(curmax, kl[j]);
                        }
                    }
                }
            }
        }
        merge_extract<K_NN>(kl, sel);
        const uint32_t d16 = sel[K_NN - 1] >> 14;
        if (d16 <= (uint32_t)(256 * r * r) || r >= rcov) break;
    }

    if (lane == 0) {
#pragma unroll
        for (int j = 0; j < K_NN; ++j) selLds[j] = sel[j];
    }
}

// ---------------- main KNN + aggregation: weight-cutoff fast path ----------------

__global__ __launch_bounds__(256) void knn_cells_kernel(
    const float* __restrict__ tfeat,   // [B, NA, C]
    const float* __restrict__ spos,    // [B, NB, 3]
    const int2*  __restrict__ meta,    // [B, NCELL] (start, count)
    const float4* __restrict__ sorted, // [B, NA] (z,y,x,idx-bits)
    float* __restrict__ out)           // [B, NB, C]
{
    __shared__ uint32_t sSel[4][16];

    const int tid  = threadIdx.x;
    const int lane = tid & 63;
    const int wave = tid >> 6;

    const int bpb = NB_ / 4;
    const int b = blockIdx.x / bpb;
    const int n = (blockIdx.x % bpb) * 4 + wave;

    const float* sp = spos + ((size_t)b * NB_ + n) * 3;
    const float s0 = sp[0], s1 = sp[1], s2 = sp[2];     // z, y, x
    const int scz = __builtin_amdgcn_readfirstlane(((int)s0) >> CSH);
    const int scy = __builtin_amdgcn_readfirstlane(((int)s1) >> CSH);
    const int scx = __builtin_amdgcn_readfirstlane(((int)s2) >> CSH);

    int rcov = max(max(scx, CX - 1 - scx), max(scy, CY - 1 - scy));
    rcov = max(rcov, max(scz, CZ - 1 - scz));

    const int2*   mb = meta   + (size_t)b * NCELL;
    const float4* sb = sorted + (size_t)b * NA_;

    // ---- 9 contiguous row-ranges of the 3x3x3 box (wave-uniform scalars) ----
    int rstart[9], rlen[9];
    const int cxlo = max(scx - 1, 0), cxhi = min(scx + 1, CX - 1);
    int nov = 0; bool fast = true;
#pragma unroll
    for (int kk = 0; kk < 9; ++kk) {
        const int cz = scz + kk / 3 - 1, cy = scy + kk % 3 - 1;
        int st = 0, ln = 0;
        if ((unsigned)cz < CZ && (unsigned)cy < CY) {
            const int rowb = (cz * CY + cy) * CX;
            const int2 mlo = mb[rowb + cxlo];
            const int2 mhi = mb[rowb + cxhi];
            st = mlo.x; ln = mhi.x + mhi.y - mlo.x;
        }
        rstart[kk] = st; rlen[kk] = ln;
        if (ln > 64) ++nov;
        if (ln > 128) fast = false;
    }
    if (nov > 3) fast = false;

    int nselF = K_NN;
    bool done = false;

    if (fast) {
        // ---------- slotted scan: no selection logic ----------
        uint32_t key[12];
#pragma unroll
        for (int j = 0; j < 12; ++j) key[j] = PADKEY + j;
        int oc = 9;
#pragma unroll
        for (int kk = 0; kk < 9; ++kk) {
            if (rlen[kk] > 0) {
                const bool act = lane < rlen[kk];
                const int a = rstart[kk] + (act ? lane : 0);
                const float4 p = sb[a];
                const float d0 = s0 - p.x, d1 = s1 - p.y, d2c = s2 - p.z;
                const float d2 = d0 * d0 + d1 * d1 + d2c * d2c;
                const uint32_t kv = ((uint32_t)d2 << 14) | (uint32_t)__float_as_int(p.w);
                key[kk] = act ? kv : key[kk];
            }
            if (rlen[kk] > 64) {
                const int j2 = 64 + lane;
                const bool act = j2 < rlen[kk];
                const int a = rstart[kk] + (act ? j2 : 0);
                const float4 p = sb[a];
                const float d0 = s0 - p.x, d1 = s1 - p.y, d2c = s2 - p.z;
                const float d2 = d0 * d0 + d1 * d1 + d2c * d2c;
                const uint32_t kv = ((uint32_t)d2 << 14) | (uint32_t)__float_as_int(p.w);
                if (oc == 9)       key[9]  = act ? kv : key[9];
                else if (oc == 10) key[10] = act ? kv : key[10];
                else               key[11] = act ? kv : key[11];
                ++oc;
            }
        }

        // ---------- wave-min reduce ----------
        uint32_t kmin = key[0];
#pragma unroll
        for (int j = 1; j < 12; ++j) kmin = min(kmin, key[j]);
#pragma unroll
        for (int off = 32; off > 0; off >>= 1)
            kmin = min(kmin, (uint32_t)__shfl_xor((int)kmin, off));
        kmin = (uint32_t)__builtin_amdgcn_readfirstlane((int)kmin);
        const uint32_t dmin2 = kmin >> 14;

        // cutoff: rel weight beyond d2min+25 is exp(-12.5) ~ 3.7e-6 (negligible);
        // completeness requires dmin2+25 <= 289 (out-of-box lower bound).
        if (dmin2 <= 264u) {
            const uint32_t keyT = (dmin2 + 25u) << 14;
            int nsel = 0;
#pragma unroll
            for (int j = 0; j < 12; ++j) {
                const bool pred = key[j] < keyT;
                const unsigned long long m = __ballot(pred);
                const int offp = __builtin_amdgcn_mbcnt_hi(
                    (uint32_t)(m >> 32), __builtin_amdgcn_mbcnt_lo((uint32_t)m, 0));
                const int dst = nsel + offp;
                if (pred && dst < K_NN) sSel[wave][dst] = key[j];
                nsel += (int)__builtin_popcountll(m);
            }
            if (nsel <= K_NN) {        // set is then a subset of the true top-16
                nselF = nsel;
                done = true;
            }
        }
    }

    if (!done)
        ring_fallback(lane, s0, s1, s2, scz, scy, scx, rcov, mb, sb, &sSel[wave][0]);
    __threadfence_block();

    // ---- broadcast winners -> wave-uniform registers (first nselF valid) ----
    const uint4 sA = *(const uint4*)&sSel[wave][0];
    const uint4 sB = *(const uint4*)&sSel[wave][4];
    const uint4 sC = *(const uint4*)&sSel[wave][8];
    const uint4 sD = *(const uint4*)&sSel[wave][12];
    uint32_t sel[K_NN];
    sel[0]  = (uint32_t)__builtin_amdgcn_readfirstlane((int)sA.x);
    sel[1]  = (uint32_t)__builtin_amdgcn_readfirstlane((int)sA.y);
    sel[2]  = (uint32_t)__builtin_amdgcn_readfirstlane((int)sA.z);
    sel[3]  = (uint32_t)__builtin_amdgcn_readfirstlane((int)sA.w);
    sel[4]  = (uint32_t)__builtin_amdgcn_readfirstlane((int)sB.x);
    sel[5]  = (uint32_t)__builtin_amdgcn_readfirstlane((int)sB.y);
    sel[6]  = (uint32_t)__builtin_amdgcn_readfirstlane((int)sB.z);
    sel[7]  = (uint32_t)__builtin_amdgcn_readfirstlane((int)sB.w);
    sel[8]  = (uint32_t)__builtin_amdgcn_readfirstlane((int)sC.x);
    sel[9]  = (uint32_t)__builtin_amdgcn_readfirstlane((int)sC.y);
    sel[10] = (uint32_t)__builtin_amdgcn_readfirstlane((int)sC.z);
    sel[11] = (uint32_t)__builtin_amdgcn_readfirstlane((int)sC.w);
    sel[12] = (uint32_t)__builtin_amdgcn_readfirstlane((int)sD.x);
    sel[13] = (uint32_t)__builtin_amdgcn_readfirstlane((int)sD.y);
    sel[14] = (uint32_t)__builtin_amdgcn_readfirstlane((int)sD.z);
    sel[15] = (uint32_t)__builtin_amdgcn_readfirstlane((int)sD.w);

    // ---- weights + normalized aggregation over the first nselF winners ----
    float w[K_NN];
    float wsum = 0.f;
#pragma unroll
    for (int j = 0; j < K_NN; ++j) {
        if (j < nselF) {
            w[j] = __expf(-0.5f * (float)(sel[j] >> 14));
            wsum += w[j];
        } else {
            w[j] = 0.f;
        }
    }
    const float inv = 1.0f / wsum;

    const float* fb = tfeat + (size_t)b * NA_ * CH;
    float2 acc = make_float2(0.f, 0.f);
#pragma unroll
    for (int j = 0; j < K_NN; ++j) {
        if (j < nselF) {
            const int idx = (int)(sel[j] & 16383u);
            const float ww = w[j] * inv;
            const float2 v = ((const float2*)(fb + (size_t)idx * CH))[lane];
            acc.x += ww * v.x; acc.y += ww * v.y;
        }
    }

    float2* o = (float2*)(out + ((size_t)b * NB_ + n) * CH);
    o[lane] = acc;
}

// ---------------- launch ----------------

extern "C" void kernel_launch(void* const* d_in, const int* in_sizes, int n_in,
                              void* d_out, int out_size, void* d_ws, size_t ws_size,
                              hipStream_t stream) {
    const float* tfeat = (const float*)d_in[0];   // [B,NA,C]
    const float* tpos  = (const float*)d_in[1];   // [B,NA,3]
    const float* spos  = (const float*)d_in[2];   // [B,NB,3]
    float* out = (float*)d_out;                   // [B,NB,C]

    char* ws = (char*)d_ws;
    int*    partial = (int*)(ws);
    int2*   meta    = (int2*)(ws + OFF_META);
    int*    cursor  = (int*)(ws + OFF_CURSOR);
    float4* sorted  = (float4*)(ws + OFF_SORTED);

    count_hist<<<16, 256, 0, stream>>>(tpos, partial);
    scan_kernel<<<BATCH, 1024, 0, stream>>>(partial, meta, cursor);
    scatter_kernel<<<(BATCH * NA_) / 256, 256, 0, stream>>>(tpos, cursor, sorted);
    knn_cells_kernel<<<BATCH * (NB_ / 4), 256, 0, stream>>>(tfeat, spos, meta, sorted, out);
}

// Round 16
// 41.773 us; speedup vs baseline: 1.9124x; 1.0303x over previous
//
#include <hip/hip_runtime.h>
#include <math.h>
#include <stdint.h>

#define K_NN   16
#define BATCH  2
#define NA_    16384
#define NB_    8192
#define CH     128
// coords are [z,y,x]: z in [0,64), y in [0,256), x in [0,256); cell edge 16
#define CZ     4
#define CY     16
#define CX     16
#define NCELL  (CZ*CY*CX)   // 1024
#define CSH    4
#define PADKEY 0xFFF00000u  // > any real key ((134019<<14)|16383 = 0x82E0BFFF)

// ws layout:
//   partial: [16][NCELL] int   @ 0      (64 KiB)
//   meta   : [B][NCELL] int2   @ 65536  (16 KiB)
//   cursor : [B][NCELL] int    @ 81920  (8 KiB)
//   sorted : [B][NA] uint2     @ 98304  (256 KiB)
#define OFF_META   65536
#define OFF_CURSOR 81920
#define OFF_SORTED 98304

__device__ __forceinline__ int cell_of(float p0, float p1, float p2) {
    const int cz = ((int)p0) >> CSH;
    const int cy = ((int)p1) >> CSH;
    const int cx = ((int)p2) >> CSH;
    return (cz * CY + cy) * CX + cx;
}

// ---------------- build 1: LDS-privatized histograms (16 blocks) ----------------

__global__ __launch_bounds__(256) void count_hist(const float* __restrict__ tpos,
                                                  int* __restrict__ partial) {
    __shared__ int h[NCELL];
    const int blk = blockIdx.x;
    const int t = threadIdx.x;
#pragma unroll
    for (int j = 0; j < NCELL / 256; ++j) h[t + j * 256] = 0;
    __syncthreads();
    const int base = blk * 2048;
#pragma unroll
    for (int i = 0; i < 8; ++i) {
        const float* p = tpos + (size_t)(base + i * 256 + t) * 3;
        atomicAdd(&h[cell_of(p[0], p[1], p[2])], 1);
    }
    __syncthreads();
#pragma unroll
    for (int j = 0; j < NCELL / 256; ++j) {
        const int c = t + j * 256;
        partial[blk * NCELL + c] = h[c];
    }
}

// ---------------- build 2: sum partials + scan (2 blocks x 1024) ----------------

__global__ __launch_bounds__(1024) void scan_kernel(const int* __restrict__ partial,
                                                    int2* __restrict__ meta,
                                                    int* __restrict__ cursor) {
    __shared__ int wp[16];
    const int b = blockIdx.x, t = threadIdx.x, lane = t & 63, w = t >> 6;
    int c = 0;
#pragma unroll
    for (int k = 0; k < 8; ++k) c += partial[(b * 8 + k) * NCELL + t];
    int x = c;
#pragma unroll
    for (int off = 1; off < 64; off <<= 1) {
        int u = __shfl_up(x, off);
        if (lane >= off) x += u;
    }
    if (lane == 63) wp[w] = x;
    __syncthreads();
    if (t < 16) {
        int v = wp[t];
#pragma unroll
        for (int off = 1; off < 16; off <<= 1) {
            int u = __shfl_up(v, off);
            if (t >= off) v += u;
        }
        wp[t] = v;
    }
    __syncthreads();
    const int excl = x - c + (w ? wp[w - 1] : 0);
    meta[b * NCELL + t]   = make_int2(excl, c);
    cursor[b * NCELL + t] = excl;
}

// ---------------- build 3: wide scatter, packed uint2 (128 blocks) ----------------

__global__ __launch_bounds__(256) void scatter_kernel(const float* __restrict__ tpos,
                                                      int* __restrict__ cursor,
                                                      uint2* __restrict__ sorted) {
    const int i = blockIdx.x * 256 + threadIdx.x;
    const int b = i >> 14;
    const float* tp = tpos + (size_t)i * 3;
    const int pz = (int)tp[0], py = (int)tp[1], px = (int)tp[2];
    const int cell = ((pz >> CSH) * CY + (py >> CSH)) * CX + (px >> CSH);
    const int pos = atomicAdd(&cursor[b * NCELL + cell], 1);
    const uint32_t pk = ((uint32_t)pz << 16) | ((uint32_t)py << 8) | (uint32_t)px;
    sorted[(size_t)b * NA_ + pos] = make_uint2(pk, (uint32_t)(i & (NA_ - 1)));
}

// ---------------- fallback merge: extract 16 smallest keys across the wave ----------------

template<int NS>
__device__ __forceinline__ void merge_extract(uint32_t (&k)[NS], uint32_t (&sel)[K_NN]) {
    uint32_t m = k[0];
#pragma unroll
    for (int j = 1; j < NS; ++j) m = min(m, k[j]);
#pragma unroll
    for (int r = 0; r < K_NN; ++r) {
        uint32_t v = m;
#pragma unroll
        for (int off = 32; off > 0; off >>= 1)
            v = min(v, (uint32_t)__shfl_xor((int)v, off));
        sel[r] = (uint32_t)__builtin_amdgcn_readfirstlane((int)v);
        if (m == v) {
#pragma unroll
            for (int j = 0; j < NS; ++j) k[j] = (k[j] == v) ? 0xFFFFFFFFu : k[j];
            m = k[0];
#pragma unroll
            for (int j = 1; j < NS; ++j) m = min(m, k[j]);
        }
    }
}

__device__ __forceinline__ uint32_t key_of(uint2 p, int sz, int sy, int sx) {
    const int pz = (int)(p.x >> 16);
    const int py = (int)((p.x >> 8) & 255u);
    const int px = (int)(p.x & 255u);
    const int dz = sz - pz, dy = sy - py, dx = sx - px;
    const uint32_t d2 = (uint32_t)(dz * dz + dy * dy + dx * dx);
    return (d2 << 14) | p.y;
}

// ---------------- exact ring fallback (rare; winners -> wave-private LDS) ----------------

__device__ __noinline__ void ring_fallback(int lane, int sz, int sy, int sx,
                                           int scz, int scy, int scx, int rcov,
                                           const int2* __restrict__ mb,
                                           const uint2* __restrict__ sb,
                                           uint32_t* selLds) {
    uint32_t sel[K_NN];
#pragma unroll
    for (int j = 0; j < K_NN; ++j) sel[j] = 0xFFFFFFFFu;

    for (int r = 1;; ++r) {
        uint32_t kl[K_NN];
#pragma unroll
        for (int j = 0; j < K_NN; ++j) kl[j] = PADKEY + 16 + j;
        if (r > 1) {
            uint32_t seed = 0xFFFFFFFFu;
#pragma unroll
            for (int j = 0; j < K_NN; ++j) if (lane == j) seed = sel[j];
            kl[0] = seed;
        }
        uint32_t curmax = kl[0];
#pragma unroll
        for (int j = 1; j < K_NN; ++j) curmax = max(curmax, kl[j]);

        for (int dz = -r; dz <= r; ++dz) {
            const int cz = scz + dz; if ((unsigned)cz >= CZ) continue;
            for (int dy = -r; dy <= r; ++dy) {
                const int cy = scy + dy; if ((unsigned)cy >= CY) continue;
                const int rowb = (cz * CY + cy) * CX;
                const bool fullrow = (r == 1) || (max(abs(dz), abs(dy)) == r);
                int xl[2], xh[2];
                if (fullrow) {
                    xl[0] = max(scx - r, 0); xh[0] = min(scx + r, CX - 1);
                    xl[1] = 1; xh[1] = 0;
                } else {
                    xl[0] = scx - r; xh[0] = scx - r;
                    xl[1] = scx + r; xh[1] = scx + r;
                    if (xl[0] < 0)      { xl[0] = 1; xh[0] = 0; }
                    if (xh[1] > CX - 1) { xl[1] = 1; xh[1] = 0; }
                }
#pragma unroll
                for (int q = 0; q < 2; ++q) {
                    if (xl[q] > xh[q]) continue;
                    const int2 mlo = mb[rowb + xl[q]];
                    const int2 mhi = mb[rowb + xh[q]];
                    const int st = mlo.x, ln = mhi.x + mhi.y - st;
                    for (int o = 0; o < ln; o += 64) {
                        const int j2 = o + lane;
                        const bool act = j2 < ln;
                        const uint2 p = sb[st + (act ? j2 : 0)];
                        uint32_t kv = key_of(p, sz, sy, sx);
                        kv = act ? kv : 0xFFFFFFFFu;
                        if (kv < curmax) {
#pragma unroll
                            for (int j = 0; j < K_NN; ++j)
                                kl[j] = (kl[j] == curmax) ? kv : kl[j];
                            curmax = kl[0];
#pragma unroll
                            for (int j = 1; j < K_NN; ++j) curmax = max(curmax, kl[j]);
                        }
                    }
                }
            }
        }
        merge_extract<K_NN>(kl, sel);
        const uint32_t d16 = sel[K_NN - 1] >> 14;
        if (d16 <= (uint32_t)(256 * r * r) || r >= rcov) break;
    }

    if (lane == 0) {
#pragma unroll
        for (int j = 0; j < K_NN; ++j) selLds[j] = sel[j];
    }
}

// ---------------- main KNN + aggregation: weight-cutoff fast path, packed points ----------------

__global__ __launch_bounds__(256) void knn_cells_kernel(
    const float* __restrict__ tfeat,   // [B, NA, C]
    const float* __restrict__ spos,    // [B, NB, 3]
    const int2*  __restrict__ meta,    // [B, NCELL] (start, count)
    const uint2* __restrict__ sorted,  // [B, NA] packed (pos, idx)
    float* __restrict__ out)           // [B, NB, C]
{
    __shared__ uint32_t sSel[4][16];

    const int tid  = threadIdx.x;
    const int lane = tid & 63;
    const int wave = tid >> 6;

    const int bpb = NB_ / 4;
    const int b = blockIdx.x / bpb;
    const int n = (blockIdx.x % bpb) * 4 + wave;

    const float* sp = spos + ((size_t)b * NB_ + n) * 3;
    const int sz = (int)sp[0], sy = (int)sp[1], sx = (int)sp[2];   // z, y, x
    const int scz = __builtin_amdgcn_readfirstlane(sz >> CSH);
    const int scy = __builtin_amdgcn_readfirstlane(sy >> CSH);
    const int scx = __builtin_amdgcn_readfirstlane(sx >> CSH);

    int rcov = max(max(scx, CX - 1 - scx), max(scy, CY - 1 - scy));
    rcov = max(rcov, max(scz, CZ - 1 - scz));

    const int2*  mb = meta   + (size_t)b * NCELL;
    const uint2* sb = sorted + (size_t)b * NA_;

    // ---- 9 contiguous row-ranges of the 3x3x3 box (wave-uniform scalars) ----
    int rstart[9], rlen[9];
    const int cxlo = max(scx - 1, 0), cxhi = min(scx + 1, CX - 1);
    int nov = 0; bool fast = true;
#pragma unroll
    for (int kk = 0; kk < 9; ++kk) {
        const int cz = scz + kk / 3 - 1, cy = scy + kk % 3 - 1;
        int st = 0, ln = 0;
        if ((unsigned)cz < CZ && (unsigned)cy < CY) {
            const int rowb = (cz * CY + cy) * CX;
            const int2 mlo = mb[rowb + cxlo];
            const int2 mhi = mb[rowb + cxhi];
            st = mlo.x; ln = mhi.x + mhi.y - mlo.x;
        }
        rstart[kk] = st; rlen[kk] = ln;
        if (ln > 64) ++nov;
        if (ln > 128) fast = false;
    }
    if (nov > 3) fast = false;

    int nselF = K_NN;
    bool done = false;

    if (fast) {
        // ---------- slotted scan ----------
        uint32_t key[12];
#pragma unroll
        for (int j = 0; j < 12; ++j) key[j] = PADKEY + j;
        int oc = 9;
#pragma unroll
        for (int kk = 0; kk < 9; ++kk) {
            if (rlen[kk] > 0) {
                const bool act = lane < rlen[kk];
                const uint2 p = sb[rstart[kk] + (act ? lane : 0)];
                const uint32_t kv = key_of(p, sz, sy, sx);
                key[kk] = act ? kv : key[kk];
            }
            if (rlen[kk] > 64) {
                const int j2 = 64 + lane;
                const bool act = j2 < rlen[kk];
                const uint2 p = sb[rstart[kk] + (act ? j2 : 0)];
                const uint32_t kv = key_of(p, sz, sy, sx);
                if (oc == 9)       key[9]  = act ? kv : key[9];
                else if (oc == 10) key[10] = act ? kv : key[10];
                else               key[11] = act ? kv : key[11];
                ++oc;
            }
        }

        // ---------- wave-min reduce ----------
        uint32_t kmin = key[0];
#pragma unroll
        for (int j = 1; j < 12; ++j) kmin = min(kmin, key[j]);
#pragma unroll
        for (int off = 32; off > 0; off >>= 1)
            kmin = min(kmin, (uint32_t)__shfl_xor((int)kmin, off));
        kmin = (uint32_t)__builtin_amdgcn_readfirstlane((int)kmin);
        const uint32_t dmin2 = kmin >> 14;

        // cutoff: rel weight beyond d2min+25 is exp(-12.5) ~ 3.7e-6 (negligible);
        // completeness requires dmin2+25 <= 289 (out-of-box lower bound).
        if (dmin2 <= 264u) {
            const uint32_t keyT = (dmin2 + 25u) << 14;
            int nsel = 0;
#pragma unroll
            for (int j = 0; j < 12; ++j) {
                const bool pred = key[j] < keyT;
                const unsigned long long m = __ballot(pred);
                const int offp = __builtin_amdgcn_mbcnt_hi(
                    (uint32_t)(m >> 32), __builtin_amdgcn_mbcnt_lo((uint32_t)m, 0));
                const int dst = nsel + offp;
                if (pred && dst < K_NN) sSel[wave][dst] = key[j];
                nsel += (int)__builtin_popcountll(m);
            }
            if (nsel <= K_NN) {        // set is then a subset of the true top-16
                nselF = nsel;
                done = true;
            }
        }
    }

    if (!done)
        ring_fallback(lane, sz, sy, sx, scz, scy, scx, rcov, mb, sb, &sSel[wave][0]);
    __threadfence_block();

    // ---- broadcast winners -> wave-uniform registers (first nselF valid) ----
    const uint4 sA = *(const uint4*)&sSel[wave][0];
    const uint4 sB = *(const uint4*)&sSel[wave][4];
    const uint4 sC = *(const uint4*)&sSel[wave][8];
    const uint4 sD = *(const uint4*)&sSel[wave][12];
    uint32_t sel[K_NN];
    sel[0]  = (uint32_t)__builtin_amdgcn_readfirstlane((int)sA.x);
    sel[1]  = (uint32_t)__builtin_amdgcn_readfirstlane((int)sA.y);
    sel[2]  = (uint32_t)__builtin_amdgcn_readfirstlane((int)sA.z);
    sel[3]  = (uint32_t)__builtin_amdgcn_readfirstlane((int)sA.w);
    sel[4]  = (uint32_t)__builtin_amdgcn_readfirstlane((int)sB.x);
    sel[5]  = (uint32_t)__builtin_amdgcn_readfirstlane((int)sB.y);
    sel[6]  = (uint32_t)__builtin_amdgcn_readfirstlane((int)sB.z);
    sel[7]  = (uint32_t)__builtin_amdgcn_readfirstlane((int)sB.w);
    sel[8]  = (uint32_t)__builtin_amdgcn_readfirstlane((int)sC.x);
    sel[9]  = (uint32_t)__builtin_amdgcn_readfirstlane((int)sC.y);
    sel[10] = (uint32_t)__builtin_amdgcn_readfirstlane((int)sC.z);
    sel[11] = (uint32_t)__builtin_amdgcn_readfirstlane((int)sC.w);
    sel[12] = (uint32_t)__builtin_amdgcn_readfirstlane((int)sD.x);
    sel[13] = (uint32_t)__builtin_amdgcn_readfirstlane((int)sD.y);
    sel[14] = (uint32_t)__builtin_amdgcn_readfirstlane((int)sD.z);
    sel[15] = (uint32_t)__builtin_amdgcn_readfirstlane((int)sD.w);

    // ---- weights over the first nselF winners (group-predicated, wave-uniform) ----
    float w[K_NN];
    float wsum = 0.f;
#pragma unroll
    for (int j = 0; j < K_NN; ++j) w[j] = 0.f;
#pragma unroll
    for (int j = 0; j < 4; ++j) {
        if (j < nselF) { w[j] = __expf(-0.5f * (float)(sel[j] >> 14)); wsum += w[j]; }
    }
    if (nselF > 4) {
#pragma unroll
        for (int j = 4; j < 8; ++j) {
            if (j < nselF) { w[j] = __expf(-0.5f * (float)(sel[j] >> 14)); wsum += w[j]; }
        }
    }
    if (nselF > 8) {
#pragma unroll
        for (int j = 8; j < 12; ++j) {
            if (j < nselF) { w[j] = __expf(-0.5f * (float)(sel[j] >> 14)); wsum += w[j]; }
        }
    }
    if (nselF > 12) {
#pragma unroll
        for (int j = 12; j < 16; ++j) {
            if (j < nselF) { w[j] = __expf(-0.5f * (float)(sel[j] >> 14)); wsum += w[j]; }
        }
    }
    const float inv = 1.0f / wsum;

    const float* fb = tfeat + (size_t)b * NA_ * CH;
    float2 acc = make_float2(0.f, 0.f);
#pragma unroll
    for (int j = 0; j < 4; ++j) {
        if (j < nselF) {
            const float2 v = ((const float2*)(fb + (size_t)(sel[j] & 16383u) * CH))[lane];
            const float ww = w[j] * inv;
            acc.x += ww * v.x; acc.y += ww * v.y;
        }
    }
    if (nselF > 4) {
#pragma unroll
        for (int j = 4; j < 8; ++j) {
            if (j < nselF) {
                const float2 v = ((const float2*)(fb + (size_t)(sel[j] & 16383u) * CH))[lane];
                const float ww = w[j] * inv;
                acc.x += ww * v.x; acc.y += ww * v.y;
            }
        }
    }
    if (nselF > 8) {
#pragma unroll
        for (int j = 8; j < 12; ++j) {
            if (j < nselF) {
                const float2 v = ((const float2*)(fb + (size_t)(sel[j] & 16383u) * CH))[lane];
                const float ww = w[j] * inv;
                acc.x += ww * v.x; acc.y += ww * v.y;
            }
        }
    }
    if (nselF > 12) {
#pragma unroll
        for (int j = 12; j < 16; ++j) {
            if (j < nselF) {
                const float2 v = ((const float2*)(fb + (size_t)(sel[j] & 16383u) * CH))[lane];
                const float ww = w[j] * inv;
                acc.x += ww * v.x; acc.y += ww * v.y;
            }
        }
    }

    float2* o = (float2*)(out + ((size_t)b * NB_ + n) * CH);
    o[lane] = acc;
}

// ---------------- launch ----------------

extern "C" void kernel_launch(void* const* d_in, const int* in_sizes, int n_in,
                              void* d_out, int out_size, void* d_ws, size_t ws_size,
                              hipStream_t stream) {
    const float* tfeat = (const float*)d_in[0];   // [B,NA,C]
    const float* tpos  = (const float*)d_in[1];   // [B,NA,3]
    const float* spos  = (const float*)d_in[2];   // [B,NB,3]
    float* out = (float*)d_out;                   // [B,NB,C]

    char* ws = (char*)d_ws;
    int*   partial = (int*)(ws);
    int2*  meta    = (int2*)(ws + OFF_META);
    int*   cursor  = (int*)(ws + OFF_CURSOR);
    uint2* sorted  = (uint2*)(ws + OFF_SORTED);

    count_hist<<<16, 256, 0, stream>>>(tpos, partial);
    scan_kernel<<<BATCH, 1024, 0, stream>>>(partial, meta, cursor);
    scatter_kernel<<<(BATCH * NA_) / 256, 256, 0, stream>>>(tpos, cursor, sorted);
    knn_cells_kernel<<<BATCH * (NB_ / 4), 256, 0, stream>>>(tfeat, spos, meta, sorted, out);
}

// Round 17
// 38.129 us; speedup vs baseline: 2.0952x; 1.0956x over previous
//
#include <hip/hip_runtime.h>
#include <math.h>
#include <stdint.h>

#define K_NN   16
#define BATCH  2
#define NA_    16384
#define NB_    8192
#define CH     128
// coords are [z,y,x]: z in [0,64), y in [0,256), x in [0,256); cell edge 16
#define CZ     4
#define CY     16
#define CX     16
#define NCELL  (CZ*CY*CX)   // 1024
#define CSH    4
#define PADKEY 0xFFF00000u  // > any real key ((134019<<14)|16383 = 0x82E0BFFF)

// ws layout:
//   partial: [16][NCELL] int   @ 0      (64 KiB)
//   meta   : [B][NCELL] int2   @ 65536  (16 KiB)
//   sorted : [B][NA] uint2     @ 98304  (256 KiB)
#define OFF_META   65536
#define OFF_SORTED 98304

__device__ __forceinline__ int cell_of(float p0, float p1, float p2) {
    const int cz = ((int)p0) >> CSH;
    const int cy = ((int)p1) >> CSH;
    const int cx = ((int)p2) >> CSH;
    return (cz * CY + cy) * CX + cx;
}

// ---------------- build 1: LDS-privatized histograms (16 blocks) ----------------

__global__ __launch_bounds__(256) void count_hist(const float* __restrict__ tpos,
                                                  int* __restrict__ partial) {
    __shared__ int h[NCELL];
    const int blk = blockIdx.x;
    const int t = threadIdx.x;
#pragma unroll
    for (int j = 0; j < NCELL / 256; ++j) h[t + j * 256] = 0;
    __syncthreads();
    const int base = blk * 2048;
#pragma unroll
    for (int i = 0; i < 8; ++i) {
        const float* p = tpos + (size_t)(base + i * 256 + t) * 3;
        atomicAdd(&h[cell_of(p[0], p[1], p[2])], 1);
    }
    __syncthreads();
#pragma unroll
    for (int j = 0; j < NCELL / 256; ++j) {
        const int c = t + j * 256;
        partial[blk * NCELL + c] = h[c];
    }
}

// ---------------- build 2: fused redundant-scan + block-local scatter (16 blocks) ----
// Block h (batch b=h>>3, local hist hl=h&7) recomputes the batch scan from partials,
// derives its own deterministic base per cell (start[c] + sum of earlier hist blocks),
// and ranks its 2048 points with LDS atomics. No inter-block communication.

__global__ __launch_bounds__(256) void scan_scatter(const float* __restrict__ tpos,
                                                    const int* __restrict__ partial,
                                                    int2* __restrict__ meta,
                                                    uint2* __restrict__ sorted) {
    __shared__ int sCur[NCELL];
    __shared__ int wp[4];

    const int h = blockIdx.x;
    const int b = h >> 3, hl = h & 7;
    const int t = threadIdx.x;
    const int lane = t & 63, w = t >> 6;

    // per-thread 4 contiguous cells: batch totals + prefix over earlier hist blocks
    int tot0 = 0, tot1 = 0, tot2 = 0, tot3 = 0;
    int pre0 = 0, pre1 = 0, pre2 = 0, pre3 = 0;
#pragma unroll
    for (int k = 0; k < 8; ++k) {
        const int4 v = *(const int4*)(partial + (b * 8 + k) * NCELL + t * 4);
        tot0 += v.x; tot1 += v.y; tot2 += v.z; tot3 += v.w;
        if (k < hl) { pre0 += v.x; pre1 += v.y; pre2 += v.z; pre3 += v.w; }
    }
    const int tsum = tot0 + tot1 + tot2 + tot3;
    int x = tsum;
#pragma unroll
    for (int off = 1; off < 64; off <<= 1) {
        int u = __shfl_up(x, off);
        if (lane >= off) x += u;
    }
    if (lane == 63) wp[w] = x;
    __syncthreads();
    if (t == 0) {
        int r = 0;
#pragma unroll
        for (int k = 0; k < 4; ++k) { const int v = wp[k]; wp[k] = r; r += v; }
    }
    __syncthreads();
    int e = x - tsum + wp[w];                  // exclusive start of cell t*4
    const int c0 = t * 4;
    if (hl == 0) {
        meta[b * NCELL + c0 + 0] = make_int2(e, tot0);
        meta[b * NCELL + c0 + 1] = make_int2(e + tot0, tot1);
        meta[b * NCELL + c0 + 2] = make_int2(e + tot0 + tot1, tot2);
        meta[b * NCELL + c0 + 3] = make_int2(e + tot0 + tot1 + tot2, tot3);
    }
    sCur[c0 + 0] = e + pre0;
    sCur[c0 + 1] = e + tot0 + pre1;
    sCur[c0 + 2] = e + tot0 + tot1 + pre2;
    sCur[c0 + 3] = e + tot0 + tot1 + tot2 + pre3;
    __syncthreads();

    // scatter this hist-block's 2048 points (block-local LDS ranking)
    const float* tb = tpos + (size_t)(b * NA_ + hl * 2048) * 3;
#pragma unroll
    for (int i = 0; i < 8; ++i) {
        const int pi = i * 256 + t;            // 0..2047 within this hist block
        const float* p = tb + (size_t)pi * 3;
        const int pz = (int)p[0], py = (int)p[1], px = (int)p[2];
        const int cell = ((pz >> CSH) * CY + (py >> CSH)) * CX + (px >> CSH);
        const int pos = atomicAdd(&sCur[cell], 1);
        const uint32_t pk = ((uint32_t)pz << 16) | ((uint32_t)py << 8) | (uint32_t)px;
        sorted[(size_t)b * NA_ + pos] = make_uint2(pk, (uint32_t)(hl * 2048 + pi));
    }
}

// ---------------- fallback merge: extract 16 smallest keys across the wave ----------------

template<int NS>
__device__ __forceinline__ void merge_extract(uint32_t (&k)[NS], uint32_t (&sel)[K_NN]) {
    uint32_t m = k[0];
#pragma unroll
    for (int j = 1; j < NS; ++j) m = min(m, k[j]);
#pragma unroll
    for (int r = 0; r < K_NN; ++r) {
        uint32_t v = m;
#pragma unroll
        for (int off = 32; off > 0; off >>= 1)
            v = min(v, (uint32_t)__shfl_xor((int)v, off));
        sel[r] = (uint32_t)__builtin_amdgcn_readfirstlane((int)v);
        if (m == v) {
#pragma unroll
            for (int j = 0; j < NS; ++j) k[j] = (k[j] == v) ? 0xFFFFFFFFu : k[j];
            m = k[0];
#pragma unroll
            for (int j = 1; j < NS; ++j) m = min(m, k[j]);
        }
    }
}

__device__ __forceinline__ uint32_t key_of(uint2 p, int sz, int sy, int sx) {
    const int pz = (int)(p.x >> 16);
    const int py = (int)((p.x >> 8) & 255u);
    const int px = (int)(p.x & 255u);
    const int dz = sz - pz, dy = sy - py, dx = sx - px;
    const uint32_t d2 = (uint32_t)(dz * dz + dy * dy + dx * dx);
    return (d2 << 14) | p.y;
}

// ---------------- exact ring fallback (rare; winners -> wave-private LDS) ----------------

__device__ __noinline__ void ring_fallback(int lane, int sz, int sy, int sx,
                                           int scz, int scy, int scx, int rcov,
                                           const int2* __restrict__ mb,
                                           const uint2* __restrict__ sb,
                                           uint32_t* selLds) {
    uint32_t sel[K_NN];
#pragma unroll
    for (int j = 0; j < K_NN; ++j) sel[j] = 0xFFFFFFFFu;

    for (int r = 1;; ++r) {
        uint32_t kl[K_NN];
#pragma unroll
        for (int j = 0; j < K_NN; ++j) kl[j] = PADKEY + 16 + j;
        if (r > 1) {
            uint32_t seed = 0xFFFFFFFFu;
#pragma unroll
            for (int j = 0; j < K_NN; ++j) if (lane == j) seed = sel[j];
            kl[0] = seed;
        }
        uint32_t curmax = kl[0];
#pragma unroll
        for (int j = 1; j < K_NN; ++j) curmax = max(curmax, kl[j]);

        for (int dz = -r; dz <= r; ++dz) {
            const int cz = scz + dz; if ((unsigned)cz >= CZ) continue;
            for (int dy = -r; dy <= r; ++dy) {
                const int cy = scy + dy; if ((unsigned)cy >= CY) continue;
                const int rowb = (cz * CY + cy) * CX;
                const bool fullrow = (r == 1) || (max(abs(dz), abs(dy)) == r);
                int xl[2], xh[2];
                if (fullrow) {
                    xl[0] = max(scx - r, 0); xh[0] = min(scx + r, CX - 1);
                    xl[1] = 1; xh[1] = 0;
                } else {
                    xl[0] = scx - r; xh[0] = scx - r;
                    xl[1] = scx + r; xh[1] = scx + r;
                    if (xl[0] < 0)      { xl[0] = 1; xh[0] = 0; }
                    if (xh[1] > CX - 1) { xl[1] = 1; xh[1] = 0; }
                }
#pragma unroll
                for (int q = 0; q < 2; ++q) {
                    if (xl[q] > xh[q]) continue;
                    const int2 mlo = mb[rowb + xl[q]];
                    const int2 mhi = mb[rowb + xh[q]];
                    const int st = mlo.x, ln = mhi.x + mhi.y - st;
                    for (int o = 0; o < ln; o += 64) {
                        const int j2 = o + lane;
                        const bool act = j2 < ln;
                        const uint2 p = sb[st + (act ? j2 : 0)];
                        uint32_t kv = key_of(p, sz, sy, sx);
                        kv = act ? kv : 0xFFFFFFFFu;
                        if (kv < curmax) {
#pragma unroll
                            for (int j = 0; j < K_NN; ++j)
                                kl[j] = (kl[j] == curmax) ? kv : kl[j];
                            curmax = kl[0];
#pragma unroll
                            for (int j = 1; j < K_NN; ++j) curmax = max(curmax, kl[j]);
                        }
                    }
                }
            }
        }
        merge_extract<K_NN>(kl, sel);
        const uint32_t d16 = sel[K_NN - 1] >> 14;
        if (d16 <= (uint32_t)(256 * r * r) || r >= rcov) break;
    }

    if (lane == 0) {
#pragma unroll
        for (int j = 0; j < K_NN; ++j) selLds[j] = sel[j];
    }
}

// ---------------- main KNN + aggregation: weight-cutoff fast path, packed points ----------------

__global__ __launch_bounds__(256) void knn_cells_kernel(
    const float* __restrict__ tfeat,   // [B, NA, C]
    const float* __restrict__ spos,    // [B, NB, 3]
    const int2*  __restrict__ meta,    // [B, NCELL] (start, count)
    const uint2* __restrict__ sorted,  // [B, NA] packed (pos, idx)
    float* __restrict__ out)           // [B, NB, C]
{
    __shared__ uint32_t sSel[4][16];

    const int tid  = threadIdx.x;
    const int lane = tid & 63;
    const int wave = tid >> 6;

    const int bpb = NB_ / 4;
    const int b = blockIdx.x / bpb;
    const int n = (blockIdx.x % bpb) * 4 + wave;

    const float* sp = spos + ((size_t)b * NB_ + n) * 3;
    const int sz = (int)sp[0], sy = (int)sp[1], sx = (int)sp[2];   // z, y, x
    const int scz = __builtin_amdgcn_readfirstlane(sz >> CSH);
    const int scy = __builtin_amdgcn_readfirstlane(sy >> CSH);
    const int scx = __builtin_amdgcn_readfirstlane(sx >> CSH);

    int rcov = max(max(scx, CX - 1 - scx), max(scy, CY - 1 - scy));
    rcov = max(rcov, max(scz, CZ - 1 - scz));

    const int2*  mb = meta   + (size_t)b * NCELL;
    const uint2* sb = sorted + (size_t)b * NA_;

    // ---- 9 contiguous row-ranges of the 3x3x3 box (wave-uniform scalars) ----
    int rstart[9], rlen[9];
    const int cxlo = max(scx - 1, 0), cxhi = min(scx + 1, CX - 1);
    int nov = 0; bool fast = true;
#pragma unroll
    for (int kk = 0; kk < 9; ++kk) {
        const int cz = scz + kk / 3 - 1, cy = scy + kk % 3 - 1;
        int st = 0, ln = 0;
        if ((unsigned)cz < CZ && (unsigned)cy < CY) {
            const int rowb = (cz * CY + cy) * CX;
            const int2 mlo = mb[rowb + cxlo];
            const int2 mhi = mb[rowb + cxhi];
            st = mlo.x; ln = mhi.x + mhi.y - mlo.x;
        }
        rstart[kk] = st; rlen[kk] = ln;
        if (ln > 64) ++nov;
        if (ln > 128) fast = false;
    }
    if (nov > 3) fast = false;

    int nselF = K_NN;
    bool done = false;

    if (fast) {
        // ---------- slotted scan ----------
        uint32_t key[12];
#pragma unroll
        for (int j = 0; j < 12; ++j) key[j] = PADKEY + j;
        int oc = 9;
#pragma unroll
        for (int kk = 0; kk < 9; ++kk) {
            if (rlen[kk] > 0) {
                const bool act = lane < rlen[kk];
                const uint2 p = sb[rstart[kk] + (act ? lane : 0)];
                const uint32_t kv = key_of(p, sz, sy, sx);
                key[kk] = act ? kv : key[kk];
            }
            if (rlen[kk] > 64) {
                const int j2 = 64 + lane;
                const bool act = j2 < rlen[kk];
                const uint2 p = sb[rstart[kk] + (act ? j2 : 0)];
                const uint32_t kv = key_of(p, sz, sy, sx);
                if (oc == 9)       key[9]  = act ? kv : key[9];
                else if (oc == 10) key[10] = act ? kv : key[10];
                else               key[11] = act ? kv : key[11];
                ++oc;
            }
        }

        // ---------- wave-min reduce ----------
        uint32_t kmin = key[0];
#pragma unroll
        for (int j = 1; j < 12; ++j) kmin = min(kmin, key[j]);
#pragma unroll
        for (int off = 32; off > 0; off >>= 1)
            kmin = min(kmin, (uint32_t)__shfl_xor((int)kmin, off));
        kmin = (uint32_t)__builtin_amdgcn_readfirstlane((int)kmin);
        const uint32_t dmin2 = kmin >> 14;

        // cutoff: rel weight beyond d2min+25 is exp(-12.5) ~ 3.7e-6 (negligible);
        // completeness requires dmin2+25 <= 289 (out-of-box lower bound).
        if (dmin2 <= 264u) {
            const uint32_t keyT = (dmin2 + 25u) << 14;
            int nsel = 0;
#pragma unroll
            for (int j = 0; j < 12; ++j) {
                const bool pred = key[j] < keyT;
                const unsigned long long m = __ballot(pred);
                const int offp = __builtin_amdgcn_mbcnt_hi(
                    (uint32_t)(m >> 32), __builtin_amdgcn_mbcnt_lo((uint32_t)m, 0));
                const int dst = nsel + offp;
                if (pred && dst < K_NN) sSel[wave][dst] = key[j];
                nsel += (int)__builtin_popcountll(m);
            }
            if (nsel <= K_NN) {        // set is then a subset of the true top-16
                nselF = nsel;
                done = true;
            }
        }
    }

    if (!done)
        ring_fallback(lane, sz, sy, sx, scz, scy, scx, rcov, mb, sb, &sSel[wave][0]);
    __threadfence_block();

    // ---- broadcast winners -> wave-uniform registers (first nselF valid) ----
    const uint4 sA = *(const uint4*)&sSel[wave][0];
    const uint4 sB = *(const uint4*)&sSel[wave][4];
    const uint4 sC = *(const uint4*)&sSel[wave][8];
    const uint4 sD = *(const uint4*)&sSel[wave][12];
    uint32_t sel[K_NN];
    sel[0]  = (uint32_t)__builtin_amdgcn_readfirstlane((int)sA.x);
    sel[1]  = (uint32_t)__builtin_amdgcn_readfirstlane((int)sA.y);
    sel[2]  = (uint32_t)__builtin_amdgcn_readfirstlane((int)sA.z);
    sel[3]  = (uint32_t)__builtin_amdgcn_readfirstlane((int)sA.w);
    sel[4]  = (uint32_t)__builtin_amdgcn_readfirstlane((int)sB.x);
    sel[5]  = (uint32_t)__builtin_amdgcn_readfirstlane((int)sB.y);
    sel[6]  = (uint32_t)__builtin_amdgcn_readfirstlane((int)sB.z);
    sel[7]  = (uint32_t)__builtin_amdgcn_readfirstlane((int)sB.w);
    sel[8]  = (uint32_t)__builtin_amdgcn_readfirstlane((int)sC.x);
    sel[9]  = (uint32_t)__builtin_amdgcn_readfirstlane((int)sC.y);
    sel[10] = (uint32_t)__builtin_amdgcn_readfirstlane((int)sC.z);
    sel[11] = (uint32_t)__builtin_amdgcn_readfirstlane((int)sC.w);
    sel[12] = (uint32_t)__builtin_amdgcn_readfirstlane((int)sD.x);
    sel[13] = (uint32_t)__builtin_amdgcn_readfirstlane((int)sD.y);
    sel[14] = (uint32_t)__builtin_amdgcn_readfirstlane((int)sD.z);
    sel[15] = (uint32_t)__builtin_amdgcn_readfirstlane((int)sD.w);

    // ---- weights over the first nselF winners (group-predicated, wave-uniform) ----
    float w[K_NN];
    float wsum = 0.f;
#pragma unroll
    for (int j = 0; j < K_NN; ++j) w[j] = 0.f;
#pragma unroll
    for (int j = 0; j < 4; ++j) {
        if (j < nselF) { w[j] = __expf(-0.5f * (float)(sel[j] >> 14)); wsum += w[j]; }
    }
    if (nselF > 4) {
#pragma unroll
        for (int j = 4; j < 8; ++j) {
            if (j < nselF) { w[j] = __expf(-0.5f * (float)(sel[j] >> 14)); wsum += w[j]; }
        }
    }
    if (nselF > 8) {
#pragma unroll
        for (int j = 8; j < 12; ++j) {
            if (j < nselF) { w[j] = __expf(-0.5f * (float)(sel[j] >> 14)); wsum += w[j]; }
        }
    }
    if (nselF > 12) {
#pragma unroll
        for (int j = 12; j < 16; ++j) {
            if (j < nselF) { w[j] = __expf(-0.5f * (float)(sel[j] >> 14)); wsum += w[j]; }
        }
    }
    const float inv = 1.0f / wsum;

    const float* fb = tfeat + (size_t)b * NA_ * CH;
    float2 acc = make_float2(0.f, 0.f);
#pragma unroll
    for (int j = 0; j < 4; ++j) {
        if (j < nselF) {
            const float2 v = ((const float2*)(fb + (size_t)(sel[j] & 16383u) * CH))[lane];
            const float ww = w[j] * inv;
            acc.x += ww * v.x; acc.y += ww * v.y;
        }
    }
    if (nselF > 4) {
#pragma unroll
        for (int j = 4; j < 8; ++j) {
            if (j < nselF) {
                const float2 v = ((const float2*)(fb + (size_t)(sel[j] & 16383u) * CH))[lane];
                const float ww = w[j] * inv;
                acc.x += ww * v.x; acc.y += ww * v.y;
            }
        }
    }
    if (nselF > 8) {
#pragma unroll
        for (int j = 8; j < 12; ++j) {
            if (j < nselF) {
                const float2 v = ((const float2*)(fb + (size_t)(sel[j] & 16383u) * CH))[lane];
                const float ww = w[j] * inv;
                acc.x += ww * v.x; acc.y += ww * v.y;
            }
        }
    }
    if (nselF > 12) {
#pragma unroll
        for (int j = 12; j < 16; ++j) {
            if (j < nselF) {
                const float2 v = ((const float2*)(fb + (size_t)(sel[j] & 16383u) * CH))[lane];
                const float ww = w[j] * inv;
                acc.x += ww * v.x; acc.y += ww * v.y;
            }
        }
    }

    float2* o = (float2*)(out + ((size_t)b * NB_ + n) * CH);
    o[lane] = acc;
}

// ---------------- launch ----------------

extern "C" void kernel_launch(void* const* d_in, const int* in_sizes, int n_in,
                              void* d_out, int out_size, void* d_ws, size_t ws_size,
                              hipStream_t stream) {
    const float* tfeat = (const float*)d_in[0];   // [B,NA,C]
    const float* tpos  = (const float*)d_in[1];   // [B,NA,3]
    const float* spos  = (const float*)d_in[2];   // [B,NB,3]
    float* out = (float*)d_out;                   // [B,NB,C]

    char* ws = (char*)d_ws;
    int*   partial = (int*)(ws);
    int2*  meta    = (int2*)(ws + OFF_META);
    uint2* sorted  = (uint2*)(ws + OFF_SORTED);

    count_hist<<<16, 256, 0, stream>>>(tpos, partial);
    scan_scatter<<<16, 256, 0, stream>>>(tpos, partial, meta, sorted);
    knn_cells_kernel<<<BATCH * (NB_ / 4), 256, 0, stream>>>(tfeat, spos, meta, sorted, out);
}

// Round 18
// 37.351 us; speedup vs baseline: 2.1388x; 1.0208x over previous
//
#include <hip/hip_runtime.h>
#include <math.h>
#include <stdint.h>

#define K_NN   16
#define BATCH  2
#define NA_    16384
#define NB_    8192
#define CH     128
// coords are [z,y,x]: z in [0,64), y in [0,256), x in [0,256); cell edge 16
#define CZ     4
#define CY     16
#define CX     16
#define NCELL  (CZ*CY*CX)   // 1024
#define CSH    4
#define PADKEY 0xFFF00000u  // > any real key ((134019<<14)|16383 = 0x82E0BFFF)

// ws layout:
//   meta   : [B][NCELL] int2   @ 65536  (16 KiB)
//   sorted : [B][NA] uint2     @ 98304  (256 KiB)
#define OFF_META   65536
#define OFF_SORTED 98304

// ---------------- single-kernel build: local hist + snapshot prefix + scatter ----------
// 16 blocks. Block h (batch b=h>>3, chunk hl=h&7, chunks of 2048 points):
// histograms ALL 8 chunks of its batch into LDS sequentially; snapshots the
// histogram right before adding chunk hl (= prefix of earlier chunks); caches its
// own chunk's packed points in registers; scans totals; scatters deterministically.

__global__ __launch_bounds__(256) void build_one(const float* __restrict__ tpos,
                                                 int2* __restrict__ meta,
                                                 uint2* __restrict__ sorted) {
    __shared__ int sH[NCELL];
    __shared__ int sP[NCELL];
    __shared__ int wp[4];

    const int h = blockIdx.x;
    const int b = h >> 3, hl = h & 7;
    const int t = threadIdx.x;
    const int lane = t & 63, w = t >> 6;

#pragma unroll
    for (int j = 0; j < 4; ++j) sH[t + j * 256] = 0;
    __syncthreads();

    const float* tb = tpos + (size_t)b * NA_ * 3;
    uint32_t mypk[8];
    int      mycell[8];

    for (int k = 0; k < 8; ++k) {
        if (k == hl) {                       // snapshot = prefix of chunks < hl
            __syncthreads();
#pragma unroll
            for (int j = 0; j < 4; ++j) sP[t + j * 256] = sH[t + j * 256];
            __syncthreads();
        }
        // thread t owns 8 contiguous points of chunk k: 96 B = 6 aligned float4
        const float4* f4 = (const float4*)(tb + (size_t)(k * 2048 + t * 8) * 3);
        const float4 f0 = f4[0], f1 = f4[1], f2 = f4[2];
        const float4 f3 = f4[3], f4v = f4[4], f5 = f4[5];
#pragma unroll
        for (int i = 0; i < 8; ++i) {
            float pzf, pyf, pxf;
            if      (i == 0) { pzf = f0.x;  pyf = f0.y;  pxf = f0.z; }
            else if (i == 1) { pzf = f0.w;  pyf = f1.x;  pxf = f1.y; }
            else if (i == 2) { pzf = f1.z;  pyf = f1.w;  pxf = f2.x; }
            else if (i == 3) { pzf = f2.y;  pyf = f2.z;  pxf = f2.w; }
            else if (i == 4) { pzf = f3.x;  pyf = f3.y;  pxf = f3.z; }
            else if (i == 5) { pzf = f3.w;  pyf = f4v.x; pxf = f4v.y; }
            else if (i == 6) { pzf = f4v.z; pyf = f4v.w; pxf = f5.x; }
            else             { pzf = f5.y;  pyf = f5.z;  pxf = f5.w; }
            const int pz = (int)pzf, py = (int)pyf, px = (int)pxf;
            const int cell = ((pz >> CSH) * CY + (py >> CSH)) * CX + (px >> CSH);
            atomicAdd(&sH[cell], 1);
            if (k == hl) {
                mypk[i] = ((uint32_t)pz << 16) | ((uint32_t)py << 8) | (uint32_t)px;
                mycell[i] = cell;
            }
        }
    }
    __syncthreads();

    // scan totals (4 contiguous cells per thread)
    const int c0 = t * 4;
    const int tot0 = sH[c0], tot1 = sH[c0 + 1], tot2 = sH[c0 + 2], tot3 = sH[c0 + 3];
    const int tsum = tot0 + tot1 + tot2 + tot3;
    int x = tsum;
#pragma unroll
    for (int off = 1; off < 64; off <<= 1) {
        int u = __shfl_up(x, off);
        if (lane >= off) x += u;
    }
    if (lane == 63) wp[w] = x;
    __syncthreads();
    if (t == 0) {
        int r = 0;
#pragma unroll
        for (int k = 0; k < 4; ++k) { const int v = wp[k]; wp[k] = r; r += v; }
    }
    __syncthreads();
    const int e = x - tsum + wp[w];
    if (hl == 0) {
        meta[b * NCELL + c0 + 0] = make_int2(e, tot0);
        meta[b * NCELL + c0 + 1] = make_int2(e + tot0, tot1);
        meta[b * NCELL + c0 + 2] = make_int2(e + tot0 + tot1, tot2);
        meta[b * NCELL + c0 + 3] = make_int2(e + tot0 + tot1 + tot2, tot3);
    }
    const int p0 = sP[c0], p1 = sP[c0 + 1], p2 = sP[c0 + 2], p3 = sP[c0 + 3];
    __syncthreads();                         // all sH reads done; reuse as cursor
    sH[c0 + 0] = e + p0;
    sH[c0 + 1] = e + tot0 + p1;
    sH[c0 + 2] = e + tot0 + tot1 + p2;
    sH[c0 + 3] = e + tot0 + tot1 + tot2 + p3;
    __syncthreads();

    // scatter own chunk (deterministic disjoint slots; block-local LDS ranking)
#pragma unroll
    for (int i = 0; i < 8; ++i) {
        const int pos = atomicAdd(&sH[mycell[i]], 1);
        sorted[(size_t)b * NA_ + pos] =
            make_uint2(mypk[i], (uint32_t)(hl * 2048 + t * 8 + i));
    }
}

// ---------------- fallback merge: extract 16 smallest keys across the wave ----------------

template<int NS>
__device__ __forceinline__ void merge_extract(uint32_t (&k)[NS], uint32_t (&sel)[K_NN]) {
    uint32_t m = k[0];
#pragma unroll
    for (int j = 1; j < NS; ++j) m = min(m, k[j]);
#pragma unroll
    for (int r = 0; r < K_NN; ++r) {
        uint32_t v = m;
#pragma unroll
        for (int off = 32; off > 0; off >>= 1)
            v = min(v, (uint32_t)__shfl_xor((int)v, off));
        sel[r] = (uint32_t)__builtin_amdgcn_readfirstlane((int)v);
        if (m == v) {
#pragma unroll
            for (int j = 0; j < NS; ++j) k[j] = (k[j] == v) ? 0xFFFFFFFFu : k[j];
            m = k[0];
#pragma unroll
            for (int j = 1; j < NS; ++j) m = min(m, k[j]);
        }
    }
}

__device__ __forceinline__ uint32_t key_of(uint2 p, int sz, int sy, int sx) {
    const int pz = (int)(p.x >> 16);
    const int py = (int)((p.x >> 8) & 255u);
    const int px = (int)(p.x & 255u);
    const int dz = sz - pz, dy = sy - py, dx = sx - px;
    const uint32_t d2 = (uint32_t)(dz * dz + dy * dy + dx * dx);
    return (d2 << 14) | p.y;
}

// ---------------- exact ring fallback (rare; winners -> wave-private LDS) ----------------

__device__ __noinline__ void ring_fallback(int lane, int sz, int sy, int sx,
                                           int scz, int scy, int scx, int rcov,
                                           const int2* __restrict__ mb,
                                           const uint2* __restrict__ sb,
                                           uint32_t* selLds) {
    uint32_t sel[K_NN];
#pragma unroll
    for (int j = 0; j < K_NN; ++j) sel[j] = 0xFFFFFFFFu;

    for (int r = 1;; ++r) {
        uint32_t kl[K_NN];
#pragma unroll
        for (int j = 0; j < K_NN; ++j) kl[j] = PADKEY + 16 + j;
        if (r > 1) {
            uint32_t seed = 0xFFFFFFFFu;
#pragma unroll
            for (int j = 0; j < K_NN; ++j) if (lane == j) seed = sel[j];
            kl[0] = seed;
        }
        uint32_t curmax = kl[0];
#pragma unroll
        for (int j = 1; j < K_NN; ++j) curmax = max(curmax, kl[j]);

        for (int dz = -r; dz <= r; ++dz) {
            const int cz = scz + dz; if ((unsigned)cz >= CZ) continue;
            for (int dy = -r; dy <= r; ++dy) {
                const int cy = scy + dy; if ((unsigned)cy >= CY) continue;
                const int rowb = (cz * CY + cy) * CX;
                const bool fullrow = (r == 1) || (max(abs(dz), abs(dy)) == r);
                int xl[2], xh[2];
                if (fullrow) {
                    xl[0] = max(scx - r, 0); xh[0] = min(scx + r, CX - 1);
                    xl[1] = 1; xh[1] = 0;
                } else {
                    xl[0] = scx - r; xh[0] = scx - r;
                    xl[1] = scx + r; xh[1] = scx + r;
                    if (xl[0] < 0)      { xl[0] = 1; xh[0] = 0; }
                    if (xh[1] > CX - 1) { xl[1] = 1; xh[1] = 0; }
                }
#pragma unroll
                for (int q = 0; q < 2; ++q) {
                    if (xl[q] > xh[q]) continue;
                    const int2 mlo = mb[rowb + xl[q]];
                    const int2 mhi = mb[rowb + xh[q]];
                    const int st = mlo.x, ln = mhi.x + mhi.y - st;
                    for (int o = 0; o < ln; o += 64) {
                        const int j2 = o + lane;
                        const bool act = j2 < ln;
                        const uint2 p = sb[st + (act ? j2 : 0)];
                        uint32_t kv = key_of(p, sz, sy, sx);
                        kv = act ? kv : 0xFFFFFFFFu;
                        if (kv < curmax) {
#pragma unroll
                            for (int j = 0; j < K_NN; ++j)
                                kl[j] = (kl[j] == curmax) ? kv : kl[j];
                            curmax = kl[0];
#pragma unroll
                            for (int j = 1; j < K_NN; ++j) curmax = max(curmax, kl[j]);
                        }
                    }
                }
            }
        }
        merge_extract<K_NN>(kl, sel);
        const uint32_t d16 = sel[K_NN - 1] >> 14;
        if (d16 <= (uint32_t)(256 * r * r) || r >= rcov) break;
    }

    if (lane == 0) {
#pragma unroll
        for (int j = 0; j < K_NN; ++j) selLds[j] = sel[j];
    }
}

// ---------------- main KNN + aggregation: weight-cutoff fast path, packed points ----------------

__global__ __launch_bounds__(256) void knn_cells_kernel(
    const float* __restrict__ tfeat,   // [B, NA, C]
    const float* __restrict__ spos,    // [B, NB, 3]
    const int2*  __restrict__ meta,    // [B, NCELL] (start, count)
    const uint2* __restrict__ sorted,  // [B, NA] packed (pos, idx)
    float* __restrict__ out)           // [B, NB, C]
{
    __shared__ uint32_t sSel[4][16];

    const int tid  = threadIdx.x;
    const int lane = tid & 63;
    const int wave = tid >> 6;

    const int bpb = NB_ / 4;
    const int b = blockIdx.x / bpb;
    const int n = (blockIdx.x % bpb) * 4 + wave;

    const float* sp = spos + ((size_t)b * NB_ + n) * 3;
    const int sz = (int)sp[0], sy = (int)sp[1], sx = (int)sp[2];   // z, y, x
    const int scz = __builtin_amdgcn_readfirstlane(sz >> CSH);
    const int scy = __builtin_amdgcn_readfirstlane(sy >> CSH);
    const int scx = __builtin_amdgcn_readfirstlane(sx >> CSH);

    int rcov = max(max(scx, CX - 1 - scx), max(scy, CY - 1 - scy));
    rcov = max(rcov, max(scz, CZ - 1 - scz));

    const int2*  mb = meta   + (size_t)b * NCELL;
    const uint2* sb = sorted + (size_t)b * NA_;

    // ---- 9 contiguous row-ranges of the 3x3x3 box (wave-uniform scalars) ----
    int rstart[9], rlen[9];
    const int cxlo = max(scx - 1, 0), cxhi = min(scx + 1, CX - 1);
    int nov = 0; bool fast = true;
#pragma unroll
    for (int kk = 0; kk < 9; ++kk) {
        const int cz = scz + kk / 3 - 1, cy = scy + kk % 3 - 1;
        int st = 0, ln = 0;
        if ((unsigned)cz < CZ && (unsigned)cy < CY) {
            const int rowb = (cz * CY + cy) * CX;
            const int2 mlo = mb[rowb + cxlo];
            const int2 mhi = mb[rowb + cxhi];
            st = mlo.x; ln = mhi.x + mhi.y - mlo.x;
        }
        rstart[kk] = st; rlen[kk] = ln;
        if (ln > 64) ++nov;
        if (ln > 128) fast = false;
    }
    if (nov > 3) fast = false;

    int nselF = K_NN;
    bool done = false;

    if (fast) {
        // ---------- slotted scan ----------
        uint32_t key[12];
#pragma unroll
        for (int j = 0; j < 12; ++j) key[j] = PADKEY + j;
        int oc = 9;
#pragma unroll
        for (int kk = 0; kk < 9; ++kk) {
            if (rlen[kk] > 0) {
                const bool act = lane < rlen[kk];
                const uint2 p = sb[rstart[kk] + (act ? lane : 0)];
                const uint32_t kv = key_of(p, sz, sy, sx);
                key[kk] = act ? kv : key[kk];
            }
            if (rlen[kk] > 64) {
                const int j2 = 64 + lane;
                const bool act = j2 < rlen[kk];
                const uint2 p = sb[rstart[kk] + (act ? j2 : 0)];
                const uint32_t kv = key_of(p, sz, sy, sx);
                if (oc == 9)       key[9]  = act ? kv : key[9];
                else if (oc == 10) key[10] = act ? kv : key[10];
                else               key[11] = act ? kv : key[11];
                ++oc;
            }
        }

        // ---------- wave-min reduce ----------
        uint32_t kmin = key[0];
#pragma unroll
        for (int j = 1; j < 12; ++j) kmin = min(kmin, key[j]);
#pragma unroll
        for (int off = 32; off > 0; off >>= 1)
            kmin = min(kmin, (uint32_t)__shfl_xor((int)kmin, off));
        kmin = (uint32_t)__builtin_amdgcn_readfirstlane((int)kmin);
        const uint32_t dmin2 = kmin >> 14;

        // cutoff: rel weight beyond d2min+25 is exp(-12.5) ~ 3.7e-6 (negligible);
        // completeness requires dmin2+25 <= 289 (out-of-box lower bound).
        if (dmin2 <= 264u) {
            const uint32_t keyT = (dmin2 + 25u) << 14;
            int nsel = 0;
#pragma unroll
            for (int j = 0; j < 12; ++j) {
                const bool pred = key[j] < keyT;
                const unsigned long long m = __ballot(pred);
                const int offp = __builtin_amdgcn_mbcnt_hi(
                    (uint32_t)(m >> 32), __builtin_amdgcn_mbcnt_lo((uint32_t)m, 0));
                const int dst = nsel + offp;
                if (pred && dst < K_NN) sSel[wave][dst] = key[j];
                nsel += (int)__builtin_popcountll(m);
            }
            if (nsel <= K_NN) {        // set is then a subset of the true top-16
                nselF = nsel;
                done = true;
            }
        }
    }

    if (!done)
        ring_fallback(lane, sz, sy, sx, scz, scy, scx, rcov, mb, sb, &sSel[wave][0]);
    __threadfence_block();

    // ---- broadcast winners -> wave-uniform registers (first nselF valid) ----
    const uint4 sA = *(const uint4*)&sSel[wave][0];
    const uint4 sB = *(const uint4*)&sSel[wave][4];
    const uint4 sC = *(const uint4*)&sSel[wave][8];
    const uint4 sD = *(const uint4*)&sSel[wave][12];
    uint32_t sel[K_NN];
    sel[0]  = (uint32_t)__builtin_amdgcn_readfirstlane((int)sA.x);
    sel[1]  = (uint32_t)__builtin_amdgcn_readfirstlane((int)sA.y);
    sel[2]  = (uint32_t)__builtin_amdgcn_readfirstlane((int)sA.z);
    sel[3]  = (uint32_t)__builtin_amdgcn_readfirstlane((int)sA.w);
    sel[4]  = (uint32_t)__builtin_amdgcn_readfirstlane((int)sB.x);
    sel[5]  = (uint32_t)__builtin_amdgcn_readfirstlane((int)sB.y);
    sel[6]  = (uint32_t)__builtin_amdgcn_readfirstlane((int)sB.z);
    sel[7]  = (uint32_t)__builtin_amdgcn_readfirstlane((int)sB.w);
    sel[8]  = (uint32_t)__builtin_amdgcn_readfirstlane((int)sC.x);
    sel[9]  = (uint32_t)__builtin_amdgcn_readfirstlane((int)sC.y);
    sel[10] = (uint32_t)__builtin_amdgcn_readfirstlane((int)sC.z);
    sel[11] = (uint32_t)__builtin_amdgcn_readfirstlane((int)sC.w);
    sel[12] = (uint32_t)__builtin_amdgcn_readfirstlane((int)sD.x);
    sel[13] = (uint32_t)__builtin_amdgcn_readfirstlane((int)sD.y);
    sel[14] = (uint32_t)__builtin_amdgcn_readfirstlane((int)sD.z);
    sel[15] = (uint32_t)__builtin_amdgcn_readfirstlane((int)sD.w);

    // ---- weights over the first nselF winners (group-predicated, wave-uniform) ----
    float w[K_NN];
    float wsum = 0.f;
#pragma unroll
    for (int j = 0; j < K_NN; ++j) w[j] = 0.f;
#pragma unroll
    for (int j = 0; j < 4; ++j) {
        if (j < nselF) { w[j] = __expf(-0.5f * (float)(sel[j] >> 14)); wsum += w[j]; }
    }
    if (nselF > 4) {
#pragma unroll
        for (int j = 4; j < 8; ++j) {
            if (j < nselF) { w[j] = __expf(-0.5f * (float)(sel[j] >> 14)); wsum += w[j]; }
        }
    }
    if (nselF > 8) {
#pragma unroll
        for (int j = 8; j < 12; ++j) {
            if (j < nselF) { w[j] = __expf(-0.5f * (float)(sel[j] >> 14)); wsum += w[j]; }
        }
    }
    if (nselF > 12) {
#pragma unroll
        for (int j = 12; j < 16; ++j) {
            if (j < nselF) { w[j] = __expf(-0.5f * (float)(sel[j] >> 14)); wsum += w[j]; }
        }
    }
    const float inv = 1.0f / wsum;

    const float* fb = tfeat + (size_t)b * NA_ * CH;
    float2 acc = make_float2(0.f, 0.f);
#pragma unroll
    for (int j = 0; j < 4; ++j) {
        if (j < nselF) {
            const float2 v = ((const float2*)(fb + (size_t)(sel[j] & 16383u) * CH))[lane];
            const float ww = w[j] * inv;
            acc.x += ww * v.x; acc.y += ww * v.y;
        }
    }
    if (nselF > 4) {
#pragma unroll
        for (int j = 4; j < 8; ++j) {
            if (j < nselF) {
                const float2 v = ((const float2*)(fb + (size_t)(sel[j] & 16383u) * CH))[lane];
                const float ww = w[j] * inv;
                acc.x += ww * v.x; acc.y += ww * v.y;
            }
        }
    }
    if (nselF > 8) {
#pragma unroll
        for (int j = 8; j < 12; ++j) {
            if (j < nselF) {
                const float2 v = ((const float2*)(fb + (size_t)(sel[j] & 16383u) * CH))[lane];
                const float ww = w[j] * inv;
                acc.x += ww * v.x; acc.y += ww * v.y;
            }
        }
    }
    if (nselF > 12) {
#pragma unroll
        for (int j = 12; j < 16; ++j) {
            if (j < nselF) {
                const float2 v = ((const float2*)(fb + (size_t)(sel[j] & 16383u) * CH))[lane];
                const float ww = w[j] * inv;
                acc.x += ww * v.x; acc.y += ww * v.y;
            }
        }
    }

    float2* o = (float2*)(out + ((size_t)b * NB_ + n) * CH);
    o[lane] = acc;
}

// ---------------- launch ----------------

extern "C" void kernel_launch(void* const* d_in, const int* in_sizes, int n_in,
                              void* d_out, int out_size, void* d_ws, size_t ws_size,
                              hipStream_t stream) {
    const float* tfeat = (const float*)d_in[0];   // [B,NA,C]
    const float* tpos  = (const float*)d_in[1];   // [B,NA,3]
    const float* spos  = (const float*)d_in[2];   // [B,NB,3]
    float* out = (float*)d_out;                   // [B,NB,C]

    char* ws = (char*)d_ws;
    int2*  meta   = (int2*)(ws + OFF_META);
    uint2* sorted = (uint2*)(ws + OFF_SORTED);

    build_one<<<16, 256, 0, stream>>>(tpos, meta, sorted);
    knn_cells_kernel<<<BATCH * (NB_ / 4), 256, 0, stream>>>(tfeat, spos, meta, sorted, out);
}